// Round 7
// baseline (315.494 us; speedup 1.0000x reference)
//
#include <hip/hip_runtime.h>

// Autoregressive GRU decoder, B=32768, H=32, T=128, fp32 in/out.
// MFMA 16x16x32 bf16, EXACT 3-way bf16 split (6 MFMAs/tile, fp32-equiv).
// Row-permuted weights make h-feedback fully lane-local (round-4/5 design).
// Two element-groups per wave (A=cols 0-15, B=16-31); rotated body pairs each
// MFMA burst with an INDEPENDENT combine.
// ROUND-7 CHANGE: r6 measured MfmaUtil 35 + VALUBusy 58 (sum 93 = serialized):
// the in-order wave issued the MFMA cluster then the combine. Force the
// interleave with sched_group_barrier ({1 MFMA, 4 VALU, 1 TRANS/2}x48 per
// pair-region, sched_barrier(0) fences), and make the y-store branchless
// (all 64 lanes hold the reduced y after the two shfl_xor; 4 same-address
// same-value stores) so each pair-region stays one basic block.
// 1024 blocks x 64 threads = 1 wave/SIMD; no LDS.

typedef __attribute__((ext_vector_type(8)))  short short8;   // 8 bf16 = 4 VGPRs
typedef __attribute__((ext_vector_type(4)))  float f32x4;

struct F3 { short8 h, m, l; };                               // 3-way split fragment

__device__ __forceinline__ void ldrow8(const float* p, float f[8]) {
    f32x4 a = *(const f32x4*)p;
    f32x4 b = *(const f32x4*)(p + 4);
    f[0]=a[0]; f[1]=a[1]; f[2]=a[2]; f[3]=a[3];
    f[4]=b[0]; f[5]=b[1]; f[6]=b[2]; f[7]=b[3];
}
__device__ __forceinline__ void ldrow8s(const float* p, float f[8], float s) {
    ldrow8(p, f);
    #pragma unroll
    for (int i = 0; i < 8; ++i) f[i] *= s;
}

// exact 3-term bf16 split of 8 fp32, packed low-k-first into bf16x2 dwords
__device__ __forceinline__ F3 split8(const float f[8]) {
    unsigned H[8], M[8], L[8];
    #pragma unroll
    for (int i = 0; i < 8; ++i) {
        unsigned a = __float_as_uint(f[i]);
        unsigned h = a & 0xffff0000u;
        float    t = f[i] - __uint_as_float(h);
        unsigned m = __float_as_uint(t) & 0xffff0000u;
        float    u = t - __uint_as_float(m);
        unsigned l = __float_as_uint(u) & 0xffff0000u;      // remainder exact
        H[i] = h; M[i] = m; L[i] = l;
    }
    union { unsigned u[4]; short8 s; } uh, um, ul;
    #pragma unroll
    for (int p = 0; p < 4; ++p) {                           // dword p = (k=2p+1, k=2p)
        uh.u[p] = __builtin_amdgcn_perm(H[2*p+1], H[2*p], 0x07060302u);
        um.u[p] = __builtin_amdgcn_perm(M[2*p+1], M[2*p], 0x07060302u);
        ul.u[p] = __builtin_amdgcn_perm(L[2*p+1], L[2*p], 0x07060302u);
    }
    F3 r; r.h = uh.s; r.m = um.s; r.l = ul.s; return r;
}

#define MFMA(a,b,c) __builtin_amdgcn_mfma_f32_16x16x32_bf16((a),(b),(c),0,0,0)

// 6-term product chain, small terms first; c0 = bias (resets acc every step)
__device__ __forceinline__ f32x4 mm6(const F3& A, const F3& B, f32x4 c) {
    c = MFMA(A.h, B.l, c);
    c = MFMA(A.l, B.h, c);
    c = MFMA(A.m, B.m, c);
    c = MFMA(A.h, B.m, c);
    c = MFMA(A.m, B.h, c);
    c = MFMA(A.h, B.h, c);
    return c;
}

__device__ __forceinline__ void mfma8(const F3 A[8], const F3& Bv,
                                      const f32x4 bC[8], f32x4 C[8]) {
    #pragma unroll
    for (int rt = 0; rt < 8; ++rt) C[rt] = mm6(A[rt], Bv, bC[rt]);
}

__device__ __forceinline__ float rcp_nr(float x) {
    float r = __builtin_amdgcn_rcpf(x);
    return r * fmaf(-x, r, 2.f);
}
// inputs pre-scaled: arN,azN = -log2e * preact ; anS,ahnS = 2*log2e * preact
__device__ __forceinline__ float comb_(float arN, float azN, float anS, float ahnS, float hp) {
    float rr = rcp_nr(1.f + __builtin_amdgcn_exp2f(arN));
    float zz = rcp_nr(1.f + __builtin_amdgcn_exp2f(azN));
    float q  = rcp_nr(__builtin_amdgcn_exp2f(fmaf(rr, ahnS, anS)) + 1.f);
    float nn = fmaf(-2.f, q, 1.f);                           // tanh
    return fmaf(zz, hp - nn, nn);
}

// one group's combine: gates->h_new (lane-local), y emit, refresh B fragment.
// Branchless store: after xor16+xor32 every lane holds the full y for its n.
__device__ __forceinline__ void combineG(const f32x4 C[8], float hp[8], F3& Bv,
                                         const float wl[4], const float wh[4],
                                         float boutv, float* op, int t) {
    float h8[8], yp = 0.f;
    #pragma unroll
    for (int r = 0; r < 4; ++r) {
        float a  = comb_(C[0][r], C[2][r], C[4][r], C[6][r], hp[r]);      // comp 8g+r
        float b2 = comb_(C[1][r], C[3][r], C[5][r], C[7][r], hp[4 + r]);  // comp 8g+4+r
        yp = fmaf(wl[r], a, yp);
        yp = fmaf(wh[r], b2, yp);
        h8[r] = a; h8[4 + r] = b2;
        hp[r] = a; hp[4 + r] = b2;
    }
    yp += __shfl_xor(yp, 16);
    yp += __shfl_xor(yp, 32);
    op[t] = yp + boutv;                   // all 64 lanes; 4 lanes/addr, same value
    Bv = split8(h8);
}

// desired emission for one {mfma8 ; combineG} pair-region:
// 48 x {1 MFMA, 4 VALU, 1 TRANS every 2nd} ; remainder floats; then fence.
__device__ __forceinline__ void sched_pair() {
    #pragma unroll
    for (int i = 0; i < 48; ++i) {
        __builtin_amdgcn_sched_group_barrier(0x008, 1, 0);   // MFMA
        __builtin_amdgcn_sched_group_barrier(0x002, 4, 0);   // VALU
        if ((i & 1) == 0)
            __builtin_amdgcn_sched_group_barrier(0x400, 1, 0); // TRANS (exp2)
    }
    __builtin_amdgcn_sched_barrier(0);
}

__global__ __launch_bounds__(64, 1)
void gru_mfma(const float* __restrict__ in_data, const float* __restrict__ hidden,
              const float* __restrict__ W_ih,   const float* __restrict__ W_hh,
              const float* __restrict__ b_ih,   const float* __restrict__ b_hh,
              const float* __restrict__ W_out,  const float* __restrict__ b_out,
              float* __restrict__ out, int B, int T)
{
    const float S_RZ = -1.44269504088896340736f;   // -log2(e)
    const float S_N  =  2.88539008177792681472f;   // 2*log2(e)

    const int lane = threadIdx.x & 63;
    const int n    = lane & 15;          // MFMA col within group; also A row
    const int g    = lane >> 4;          // k-group: B k-slice 8g..8g+7
    const int k0   = g * 8;
    const long eA  = (long)blockIdx.x * 32 + n;        // group A element
    const long eB  = eA + 16;                          // group B element

    // permuted weight-row mapping (C rows 4g+r -> comps 8g+r / 8g+4+r):
    const int rlo = 8 * (n >> 2) + (n & 3);
    const int rhi = rlo + 4;

    // ---- biases in C layout, pre-scaled ----
    f32x4 bC[8];
    #pragma unroll
    for (int p = 0; p < 2; ++p) {
        #pragma unroll
        for (int r = 0; r < 4; ++r) {
            const int c = 8 * g + 4 * p + r;
            bC[0 + p][r] = S_RZ * (b_ih[c]      + b_hh[c]);       // r
            bC[2 + p][r] = S_RZ * (b_ih[32 + c] + b_hh[32 + c]);  // z
            bC[4 + p][r] = S_N  *  b_ih[64 + c];                  // i_n
            bC[6 + p][r] = S_N  *  b_hh[64 + c];                  // h_n
        }
    }
    float wl[4], wh[4];
    #pragma unroll
    for (int r = 0; r < 4; ++r) { wl[r] = W_out[8*g + r]; wh[r] = W_out[8*g + 4 + r]; }
    const float boutv = b_out[0];
    float* const opA = out + eA * (long)T;
    float* const opB = out + eB * (long)T;

    // ---- initial h and x fragments for both groups ----
    float hpA[8], hpB[8];
    F3 BvA, BvB, BxA, BxB;
    {
        float f[8];
        ldrow8(hidden + eA * 32 + k0, f);
        #pragma unroll
        for (int i = 0; i < 8; ++i) hpA[i] = f[i];
        BvA = split8(f);
        ldrow8(hidden + eB * 32 + k0, f);
        #pragma unroll
        for (int i = 0; i < 8; ++i) hpB[i] = f[i];
        BvB = split8(f);
        ldrow8(in_data + eA * 32 + k0, f); BxA = split8(f);
        ldrow8(in_data + eB * 32 + k0, f); BxB = split8(f);
    }

    F3 A[8];
    f32x4 CA[8], CB[8];

    // ---- step 0, x-phase: scaled W_ih tiles {r,z,n} x {lo,hi} ----
    #pragma unroll
    for (int gs = 0; gs < 3; ++gs) {
        const float s = (gs < 2) ? S_RZ : S_N;
        float fl[8], fh[8];
        ldrow8s(W_ih + (gs * 32 + rlo) * 32 + k0, fl, s);
        ldrow8s(W_ih + (gs * 32 + rhi) * 32 + k0, fh, s);
        A[2*gs] = split8(fl); A[2*gs+1] = split8(fh);
    }
    #pragma unroll
    for (int rt = 0; rt < 6; ++rt) { CA[rt] = mm6(A[rt], BxA, bC[rt]);
                                     CB[rt] = mm6(A[rt], BxB, bC[rt]); }

    // ---- step 0, h-phase: scaled W_hh; r,z accumulate; h_n -> C6,C7 ----
    #pragma unroll
    for (int gs = 0; gs < 3; ++gs) {
        const float s = (gs < 2) ? S_RZ : S_N;
        float fl[8], fh[8];
        ldrow8s(W_hh + (gs * 32 + rlo) * 32 + k0, fl, s);
        ldrow8s(W_hh + (gs * 32 + rhi) * 32 + k0, fh, s);
        A[2*gs] = split8(fl); A[2*gs+1] = split8(fh);
    }
    #pragma unroll
    for (int rt = 0; rt < 4; ++rt) { CA[rt] = mm6(A[rt], BvA, CA[rt]);
                                     CB[rt] = mm6(A[rt], BvB, CB[rt]); }
    CA[6] = mm6(A[4], BvA, bC[6]);  CB[6] = mm6(A[4], BvB, bC[6]);
    CA[7] = mm6(A[5], BvA, bC[7]);  CB[7] = mm6(A[5], BvB, bC[7]);

    // ---- fused weights for t>=1 (x==h): r,z = s*(Wih+Whh); i_n; h_n ----
    #pragma unroll
    for (int gs = 0; gs < 2; ++gs) {
        float fl[8], fh[8], g2[8];
        ldrow8(W_ih + (gs * 32 + rlo) * 32 + k0, fl);
        ldrow8(W_hh + (gs * 32 + rlo) * 32 + k0, g2);
        #pragma unroll
        for (int i = 0; i < 8; ++i) fl[i] = S_RZ * (fl[i] + g2[i]);
        ldrow8(W_ih + (gs * 32 + rhi) * 32 + k0, fh);
        ldrow8(W_hh + (gs * 32 + rhi) * 32 + k0, g2);
        #pragma unroll
        for (int i = 0; i < 8; ++i) fh[i] = S_RZ * (fh[i] + g2[i]);
        A[2*gs] = split8(fl); A[2*gs+1] = split8(fh);
    }
    {
        float fl[8], fh[8];
        ldrow8s(W_ih + (64 + rlo) * 32 + k0, fl, S_N);
        ldrow8s(W_ih + (64 + rhi) * 32 + k0, fh, S_N);
        A[4] = split8(fl); A[5] = split8(fh);
        ldrow8s(W_hh + (64 + rlo) * 32 + k0, fl, S_N);
        ldrow8s(W_hh + (64 + rhi) * 32 + k0, fh, S_N);
        A[6] = split8(fl); A[7] = split8(fh);
    }

    // ---- rotated pipeline: prologue combineA(0) ----
    combineG(CA, hpA, BvA, wl, wh, boutv, opA, 0);
    __builtin_amdgcn_sched_barrier(0);

    // body t: [mfma8_A || combineB(t)] ; [mfma8_B || combineA(t+1)]
    // sched_group_barrier forces the MFMA/VALU interleave in each pair-region.
    #pragma unroll 1
    for (int t = 0; t < T - 1; ++t) {
        mfma8(A, BvA, bC, CA);
        combineG(CB, hpB, BvB, wl, wh, boutv, opB, t);
        sched_pair();
        mfma8(A, BvB, bC, CB);
        combineG(CA, hpA, BvA, wl, wh, boutv, opA, t + 1);
        sched_pair();
    }

    // epilogue: combineB(T-1)
    combineG(CB, hpB, BvB, wl, wh, boutv, opB, T - 1);
}

extern "C" void kernel_launch(void* const* d_in, const int* in_sizes, int n_in,
                              void* d_out, int out_size, void* d_ws, size_t ws_size,
                              hipStream_t stream) {
    const float* in_data = (const float*)d_in[0];
    const float* hidden  = (const float*)d_in[1];
    const float* W_ih    = (const float*)d_in[2];
    const float* W_hh    = (const float*)d_in[3];
    const float* b_ih    = (const float*)d_in[4];
    const float* b_hh    = (const float*)d_in[5];
    const float* W_out   = (const float*)d_in[6];
    const float* b_out   = (const float*)d_in[7];
    float* out = (float*)d_out;

    const int B = in_sizes[0] / 32;       // 32768
    const int T = out_size / B;           // 128
    const int blocks = B / 32;            // 32 elems per 64-thread (1-wave) block

    gru_mfma<<<blocks, 64, 0, stream>>>(in_data, hidden, W_ih, W_hh,
                                        b_ih, b_hh, W_out, b_out, out, B, T);
}

// Round 8
// 277.463 us; speedup vs baseline: 1.1371x; 1.1371x over previous
//
#include <hip/hip_runtime.h>

// Autoregressive GRU decoder, B=32768, H=32, T=128, fp32 in/out.
// MFMA 16x16x32 bf16, EXACT 3-way bf16 split (6 MFMAs/tile, fp32-equiv).
// Row-permuted weights make h-feedback fully lane-local (round-4+ design).
// ROUND-8 CHANGES (r7 post-mortem: VALUBusy includes MFMA; step = serialized
// legs MFMA | VALU | TRANS | stalls; 1 wave/SIMD has no bubble-filler):
//  (1) y via MFMA: 9th A-tile with EVERY row = W_out -> each lane's C rows of
//      that tile all equal y(element). Kills the 2 shfl_xor DS-waits and the
//      y-FMA chain; b_out folded into the y tile's C-in bias. 6-term split
//      for y (error ~1e-7, negligible vs 1e-3 scale).
//  (2) 2 waves/SIMD anti-phase: 128-thread blocks, 16 elems/wave; waves in an
//      odd SIMD slot (HW_ID.wave_id & 1) s_sleep ~1150 cyc once before the
//      loop -> their MFMA leg overlaps the partner wave's combine/TRANS leg.
//      s_setprio(1) around the MFMA burst reinforces the separation.
// No LDS, no barriers. 1024 blocks x 128 threads = 2048 waves = 2/SIMD.

typedef __attribute__((ext_vector_type(8)))  short short8;   // 8 bf16 = 4 VGPRs
typedef __attribute__((ext_vector_type(4)))  float f32x4;

struct F3 { short8 h, m, l; };                               // 3-way split fragment

__device__ __forceinline__ void ldrow8(const float* p, float f[8]) {
    f32x4 a = *(const f32x4*)p;
    f32x4 b = *(const f32x4*)(p + 4);
    f[0]=a[0]; f[1]=a[1]; f[2]=a[2]; f[3]=a[3];
    f[4]=b[0]; f[5]=b[1]; f[6]=b[2]; f[7]=b[3];
}
__device__ __forceinline__ void ldrow8s(const float* p, float f[8], float s) {
    ldrow8(p, f);
    #pragma unroll
    for (int i = 0; i < 8; ++i) f[i] *= s;
}

// exact 3-term bf16 split of 8 fp32, packed low-k-first into bf16x2 dwords
__device__ __forceinline__ F3 split8(const float f[8]) {
    unsigned H[8], M[8], L[8];
    #pragma unroll
    for (int i = 0; i < 8; ++i) {
        unsigned a = __float_as_uint(f[i]);
        unsigned h = a & 0xffff0000u;
        float    t = f[i] - __uint_as_float(h);
        unsigned m = __float_as_uint(t) & 0xffff0000u;
        float    u = t - __uint_as_float(m);
        unsigned l = __float_as_uint(u) & 0xffff0000u;      // remainder exact
        H[i] = h; M[i] = m; L[i] = l;
    }
    union { unsigned u[4]; short8 s; } uh, um, ul;
    #pragma unroll
    for (int p = 0; p < 4; ++p) {                           // dword p = (k=2p+1, k=2p)
        uh.u[p] = __builtin_amdgcn_perm(H[2*p+1], H[2*p], 0x07060302u);
        um.u[p] = __builtin_amdgcn_perm(M[2*p+1], M[2*p], 0x07060302u);
        ul.u[p] = __builtin_amdgcn_perm(L[2*p+1], L[2*p], 0x07060302u);
    }
    F3 r; r.h = uh.s; r.m = um.s; r.l = ul.s; return r;
}

#define MFMA(a,b,c) __builtin_amdgcn_mfma_f32_16x16x32_bf16((a),(b),(c),0,0,0)

// 6-term product chain, small terms first; c0 = bias (resets acc every step)
__device__ __forceinline__ f32x4 mm6(const F3& A, const F3& B, f32x4 c) {
    c = MFMA(A.h, B.l, c);
    c = MFMA(A.l, B.h, c);
    c = MFMA(A.m, B.m, c);
    c = MFMA(A.h, B.m, c);
    c = MFMA(A.m, B.h, c);
    c = MFMA(A.h, B.h, c);
    return c;
}

__device__ __forceinline__ float rcp_nr(float x) {
    float r = __builtin_amdgcn_rcpf(x);
    return r * fmaf(-x, r, 2.f);
}
// inputs pre-scaled: arN,azN = -log2e * preact ; anS,ahnS = 2*log2e * preact
__device__ __forceinline__ float comb_(float arN, float azN, float anS, float ahnS, float hp) {
    float rr = rcp_nr(1.f + __builtin_amdgcn_exp2f(arN));
    float zz = rcp_nr(1.f + __builtin_amdgcn_exp2f(azN));
    float q  = rcp_nr(__builtin_amdgcn_exp2f(fmaf(rr, ahnS, anS)) + 1.f);
    float nn = fmaf(-2.f, q, 1.f);                           // tanh
    return fmaf(zz, hp - nn, nn);
}

// gates -> h_new (lane-local), refresh B fragment. No y work here (y = MFMA).
__device__ __forceinline__ void combineG(const f32x4 C[8], float hp[8], F3& Bv) {
    float h8[8];
    #pragma unroll
    for (int r = 0; r < 4; ++r) {
        float a  = comb_(C[0][r], C[2][r], C[4][r], C[6][r], hp[r]);      // comp 8g+r
        float b2 = comb_(C[1][r], C[3][r], C[5][r], C[7][r], hp[4 + r]);  // comp 8g+4+r
        h8[r] = a; h8[4 + r] = b2;
        hp[r] = a; hp[4 + r] = b2;
    }
    Bv = split8(h8);
}

__global__ __launch_bounds__(128, 2)
void gru_mfma(const float* __restrict__ in_data, const float* __restrict__ hidden,
              const float* __restrict__ W_ih,   const float* __restrict__ W_hh,
              const float* __restrict__ b_ih,   const float* __restrict__ b_hh,
              const float* __restrict__ W_out,  const float* __restrict__ b_out,
              float* __restrict__ out, int B, int T)
{
    const float S_RZ = -1.44269504088896340736f;   // -log2(e)
    const float S_N  =  2.88539008177792681472f;   // 2*log2(e)

    const int tid  = threadIdx.x;
    const int lane = tid & 63;
    const int wv   = tid >> 6;           // wave within block (0/1)
    const int n    = lane & 15;          // MFMA col = batch element; also A row
    const int g    = lane >> 4;          // k-group: B k-slice 8g..8g+7
    const int k0   = g * 8;
    const long e   = (long)blockIdx.x * 32 + wv * 16 + n;   // batch element

    // permuted weight-row mapping (C rows 4g+r -> comps 8g+r / 8g+4+r):
    const int rlo = 8 * (n >> 2) + (n & 3);
    const int rhi = rlo + 4;

    // ---- biases in C layout, pre-scaled ----
    f32x4 bC[8];
    #pragma unroll
    for (int p = 0; p < 2; ++p) {
        #pragma unroll
        for (int r = 0; r < 4; ++r) {
            const int c = 8 * g + 4 * p + r;
            bC[0 + p][r] = S_RZ * (b_ih[c]      + b_hh[c]);       // r
            bC[2 + p][r] = S_RZ * (b_ih[32 + c] + b_hh[32 + c]);  // z
            bC[4 + p][r] = S_N  *  b_ih[64 + c];                  // i_n
            bC[6 + p][r] = S_N  *  b_hh[64 + c];                  // h_n
        }
    }
    f32x4 bC8;                                     // y tile C-in = b_out
    { float bo = b_out[0]; bC8[0]=bo; bC8[1]=bo; bC8[2]=bo; bC8[3]=bo; }
    float* const op = out + e * (long)T;

    // ---- initial h and x fragments ----
    float hp[8];
    F3 Bv, Bx;
    {
        float f[8];
        ldrow8(hidden + e * 32 + k0, f);
        #pragma unroll
        for (int i = 0; i < 8; ++i) hp[i] = f[i];
        Bv = split8(f);
        ldrow8(in_data + e * 32 + k0, f); Bx = split8(f);
    }

    F3 A[8], Ay;
    f32x4 C[8], Cy;

    // y tile: EVERY A row = W_out (lane loads W_out[k0..k0+7] regardless of n)
    { float f[8]; ldrow8(W_out + k0, f); Ay = split8(f); }

    // ---- step 0, x-phase: scaled W_ih tiles {r,z,n} x {lo,hi} ----
    #pragma unroll
    for (int gs = 0; gs < 3; ++gs) {
        const float s = (gs < 2) ? S_RZ : S_N;
        float fl[8], fh[8];
        ldrow8s(W_ih + (gs * 32 + rlo) * 32 + k0, fl, s);
        ldrow8s(W_ih + (gs * 32 + rhi) * 32 + k0, fh, s);
        A[2*gs] = split8(fl); A[2*gs+1] = split8(fh);
    }
    #pragma unroll
    for (int rt = 0; rt < 6; ++rt) C[rt] = mm6(A[rt], Bx, bC[rt]);

    // ---- step 0, h-phase: scaled W_hh; r,z accumulate; h_n -> C6,C7 ----
    #pragma unroll
    for (int gs = 0; gs < 3; ++gs) {
        const float s = (gs < 2) ? S_RZ : S_N;
        float fl[8], fh[8];
        ldrow8s(W_hh + (gs * 32 + rlo) * 32 + k0, fl, s);
        ldrow8s(W_hh + (gs * 32 + rhi) * 32 + k0, fh, s);
        A[2*gs] = split8(fl); A[2*gs+1] = split8(fh);
    }
    #pragma unroll
    for (int rt = 0; rt < 4; ++rt) C[rt] = mm6(A[rt], Bv, C[rt]);
    C[6] = mm6(A[4], Bv, bC[6]);
    C[7] = mm6(A[5], Bv, bC[7]);

    // ---- fused weights for t>=1 (x==h): r,z = s*(Wih+Whh); i_n; h_n ----
    #pragma unroll
    for (int gs = 0; gs < 2; ++gs) {
        float fl[8], fh[8], g2[8];
        ldrow8(W_ih + (gs * 32 + rlo) * 32 + k0, fl);
        ldrow8(W_hh + (gs * 32 + rlo) * 32 + k0, g2);
        #pragma unroll
        for (int i = 0; i < 8; ++i) fl[i] = S_RZ * (fl[i] + g2[i]);
        ldrow8(W_ih + (gs * 32 + rhi) * 32 + k0, fh);
        ldrow8(W_hh + (gs * 32 + rhi) * 32 + k0, g2);
        #pragma unroll
        for (int i = 0; i < 8; ++i) fh[i] = S_RZ * (fh[i] + g2[i]);
        A[2*gs] = split8(fl); A[2*gs+1] = split8(fh);
    }
    {
        float fl[8], fh[8];
        ldrow8s(W_ih + (64 + rlo) * 32 + k0, fl, S_N);
        ldrow8s(W_ih + (64 + rhi) * 32 + k0, fh, S_N);
        A[4] = split8(fl); A[5] = split8(fh);
        ldrow8s(W_hh + (64 + rlo) * 32 + k0, fl, S_N);
        ldrow8s(W_hh + (64 + rhi) * 32 + k0, fh, S_N);
        A[6] = split8(fl); A[7] = split8(fh);
    }

    // ---- combine(0): h_0, Bv = split(h_0) ----
    combineG(C, hp, Bv);

    // ---- anti-phase stagger: odd SIMD-slot waves sleep ~1150 cyc once ----
    // HW_ID (id=4) wave_id bits [3:0]: imm = (size-1)<<11 | offset<<6 | id
    {
        int wslot = __builtin_amdgcn_s_getreg((3 << 11) | (0 << 6) | 4);
        if (wslot & 1) __builtin_amdgcn_s_sleep(18);
    }

    // ---- main loop: MFMA phase (gates t+1, y_t) ; combine(t+1) ; store y_t ----
    #pragma unroll 1
    for (int t = 0; t < T - 1; ++t) {
        __builtin_amdgcn_s_setprio(1);
        #pragma unroll
        for (int rt = 0; rt < 8; ++rt) C[rt] = mm6(A[rt], Bv, bC[rt]);
        Cy = mm6(Ay, Bv, bC8);                       // y_t = W_out . h_t + b_out
        __builtin_amdgcn_s_setprio(0);
        combineG(C, hp, Bv);                          // h_{t+1}
        op[t] = Cy[0];                                // all lanes; dups same value
    }

    // ---- tail: y_{T-1} ----
    Cy = mm6(Ay, Bv, bC8);
    op[T - 1] = Cy[0];
}

extern "C" void kernel_launch(void* const* d_in, const int* in_sizes, int n_in,
                              void* d_out, int out_size, void* d_ws, size_t ws_size,
                              hipStream_t stream) {
    const float* in_data = (const float*)d_in[0];
    const float* hidden  = (const float*)d_in[1];
    const float* W_ih    = (const float*)d_in[2];
    const float* W_hh    = (const float*)d_in[3];
    const float* b_ih    = (const float*)d_in[4];
    const float* b_hh    = (const float*)d_in[5];
    const float* W_out   = (const float*)d_in[6];
    const float* b_out   = (const float*)d_in[7];
    float* out = (float*)d_out;

    const int B = in_sizes[0] / 32;       // 32768
    const int T = out_size / B;           // 128
    const int blocks = B / 32;            // 16 elems/wave * 2 waves/block

    gru_mfma<<<blocks, 128, 0, stream>>>(in_data, hidden, W_ih, W_hh,
                                         b_ih, b_hh, W_out, b_out, out, B, T);
}